// Round 4
// baseline (178.368 us; speedup 1.0000x reference)
//
#include <hip/hip_runtime.h>
#include <hip/hip_bf16.h>
#include <math.h>

#define HW_   65536
#define B_    2
#define Q_    100
#define C_    134
#define T_    20
#define NHUN  100
#define S2_   16
#define CH2   4096            // elements per slice
#define NIT   4               // iters per block (CH2/1024)
#define NPART 48              // padded partial record (42 used)

// ws layout (floats):
#define LABPS_OFF  0                       // [40][16] lab partial sums
#define CC_OFF     640                     // [200][20]
#define COST_OFF   4640                    // [200][20]
#define BASE_END   8640
#define LABC_OFF   BASE_END                // [2][16][4][20][1024] = 2,621,440
#define LABC_SZ    (B_ * S2_ * NIT * T_ * 1024)
#define PART_OFF   (LABC_OFF + LABC_SZ)    // 3200 records * 48
#define T1_END     (PART_OFF + S2_ * B_ * Q_ * NPART)

__device__ inline float softplusf(float x) {
    float ax = fabsf(x);
    return fmaxf(x, 0.0f) + log1pf(expf(-ax));
}

// ---------------- K1: decimate mask_labels into coalesced labC + per-slice sums ----------------
// grid (B_, S2_), 256 threads. labC[(b*S2_+s)*81920 + (it*20+t)*1024 + tid*4 + e]
//   = ml[b][t][ decimated k = s*4096 + it*1024 + tid*4 + e ]
__global__ void lab_prep_kernel(const float* __restrict__ ml, float* __restrict__ lab_ps,
                                float* __restrict__ labC, int compact) {
    int b   = blockIdx.x;
    int s   = blockIdx.y;
    int tid = threadIdx.x;
    const float* mlb = ml + (size_t)b * T_ * 262144;
    float* outb = labC + (size_t)(b * S2_ + s) * (NIT * T_ * 1024);
    float tacc[T_];
#pragma unroll
    for (int t = 0; t < T_; ++t) tacc[t] = 0.f;

    for (int it = 0; it < NIT; ++it) {
        int k0 = s * CH2 + it * 1024 + tid * 4;
        int r  = k0 >> 8;            // decimated row (0..255)
        int c  = k0 & 255;           // decimated col, multiple of 4
        for (int t = 0; t < T_; ++t) {
            const float* src = mlb + (size_t)t * 262144 + r * 1024 + 2 * c;
            float4 u = ((const float4*)src)[0];
            float4 w = ((const float4*)src)[1];
            float4 v = make_float4(u.x, u.z, w.x, w.z);
            if (compact) ((float4*)(outb + (it * T_ + t) * 1024))[tid] = v;
            tacc[t] += v.x + v.y + v.z + v.w;
        }
    }
    __shared__ float sb[4][T_];
    int wid = tid >> 6, lane = tid & 63;
#pragma unroll
    for (int t = 0; t < T_; ++t) {
        float a = tacc[t];
        for (int off = 32; off > 0; off >>= 1) a += __shfl_down(a, off);
        if (lane == 0) sb[wid][t] = a;
    }
    __syncthreads();
    if (tid < T_) {
        lab_ps[(b * T_ + tid) * S2_ + s] = sb[0][tid] + sb[1][tid] + sb[2][tid] + sb[3][tid];
    }
}

// ---------------- K2: cc[b,q,t] = -softmax(class_logits)[class_labels[b,t]] ----------------
__global__ void class_cost_kernel(const float* __restrict__ cl, const int* __restrict__ labels,
                                  float* __restrict__ cc) {
    int bq  = blockIdx.x;          // 0..199
    int b   = bq / Q_;
    int tid = threadIdx.x;         // 64
    __shared__ float sl[C_];
    const float* src = cl + (size_t)bq * C_;
    for (int c = tid; c < C_; c += 64) sl[c] = src[c];
    __syncthreads();
    float mx = -INFINITY;
    for (int c = tid; c < C_; c += 64) mx = fmaxf(mx, sl[c]);
    for (int off = 32; off > 0; off >>= 1) mx = fmaxf(mx, __shfl_xor(mx, off));
    float se = 0.f;
    for (int c = tid; c < C_; c += 64) se += expf(sl[c] - mx);
    for (int off = 32; off > 0; off >>= 1) se += __shfl_xor(se, off);
    float inv = 1.0f / se;
    if (tid < T_) {
        int lbl = labels[b * T_ + tid];
        cc[bq * T_ + tid] = -expf(sl[lbl] - mx) * inv;
    }
}

// ---------------- K3: focal/dice partials, 2 queries per block, coalesced lab ----------------
// blockIdx.x = s*(B_*50) + b*50 + qg   (q fastest -> lab chunk shared in L2)
__global__ __launch_bounds__(256) void focal2_kernel(
        const float* __restrict__ mq, const float* __restrict__ labC,
        float* __restrict__ part) {
    int idx = blockIdx.x;              // 0..1599
    int s   = idx / (B_ * 50);
    int rem = idx % (B_ * 50);
    int b   = rem / 50;
    int qg  = rem % 50;
    int tid = threadIdx.x;             // 256

    const float* labB = labC + (size_t)(b * S2_ + s) * (NIT * T_ * 1024);
    const float* x0   = mq + (size_t)(b * Q_ + qg * 2) * HW_ + s * CH2;
    const float* x1   = x0 + HW_;

    float a1[2][T_], a2[2][T_];
#pragma unroll
    for (int q = 0; q < 2; ++q)
#pragma unroll
        for (int t = 0; t < T_; ++t) { a1[q][t] = 0.f; a2[q][t] = 0.f; }
    float Fq[2] = {0.f, 0.f}, Pq[2] = {0.f, 0.f};

    for (int it = 0; it < NIT; ++it) {
        float4 xv[2];
        xv[0] = ((const float4*)(x0 + it * 1024))[tid];
        xv[1] = ((const float4*)(x1 + it * 1024))[tid];
        float pv[2][4], dv[2][4];
#pragma unroll
        for (int q = 0; q < 2; ++q) {
#pragma unroll
            for (int e = 0; e < 4; ++e) {
                float x  = (&xv[q].x)[e];
                float ax = fabsf(x);
                float a  = __expf(-ax);
                float rr = 1.0f / (1.0f + a);
                float p  = (x >= 0.f) ? rr : a * rr;
                float om = (x >= 0.f) ? a * rr : rr;
                float l1 = __logf(1.0f + a);
                float spn = fmaxf(-x, 0.f) + l1;     // softplus(-x)
                float spp = spn + x;                  // softplus(x)
                float fp = 0.25f * om * om * spn;
                float fn = 0.75f * p * p * spp;
                pv[q][e] = p; dv[q][e] = fp - fn;
                Fq[q] += fn; Pq[q] += p;
            }
        }
        const float4* lb = (const float4*)(labB + it * (T_ * 1024)) + tid;
#pragma unroll
        for (int t = 0; t < T_; ++t) {
            float4 l4 = lb[t * 256];
#pragma unroll
            for (int q = 0; q < 2; ++q) {
                float u1 = a1[q][t], u2 = a2[q][t];
                u1 = fmaf(dv[q][0], l4.x, u1); u2 = fmaf(pv[q][0], l4.x, u2);
                u1 = fmaf(dv[q][1], l4.y, u1); u2 = fmaf(pv[q][1], l4.y, u2);
                u1 = fmaf(dv[q][2], l4.z, u1); u2 = fmaf(pv[q][2], l4.z, u2);
                u1 = fmaf(dv[q][3], l4.w, u1); u2 = fmaf(pv[q][3], l4.w, u2);
                a1[q][t] = u1; a2[q][t] = u2;
            }
        }
    }

    // deterministic reduction: wave shfl, then cross-wave LDS
    __shared__ float sbuf[4][2 * 42];
    int wid = tid >> 6, lane = tid & 63;
#pragma unroll
    for (int q = 0; q < 2; ++q) {
#pragma unroll
        for (int t = 0; t < T_; ++t) {
            float u1 = a1[q][t], u2 = a2[q][t];
            for (int off = 32; off > 0; off >>= 1) {
                u1 += __shfl_down(u1, off);
                u2 += __shfl_down(u2, off);
            }
            if (lane == 0) { sbuf[wid][q * 42 + t] = u1; sbuf[wid][q * 42 + T_ + t] = u2; }
        }
        float f = Fq[q], p = Pq[q];
        for (int off = 32; off > 0; off >>= 1) { f += __shfl_down(f, off); p += __shfl_down(p, off); }
        if (lane == 0) { sbuf[wid][q * 42 + 40] = f; sbuf[wid][q * 42 + 41] = p; }
    }
    __syncthreads();
    if (tid < 84) {
        float v = sbuf[0][tid] + sbuf[1][tid] + sbuf[2][tid] + sbuf[3][tid];
        int q = tid / 42, r = tid % 42;
        part[((size_t)(s * (B_ * Q_) + b * Q_ + qg * 2 + q)) * NPART + r] = v;
    }
}

// ---------------- K4: compose final cost ----------------
__global__ void compose_kernel(const float* __restrict__ part, const float* __restrict__ cc,
                               const float* __restrict__ lab_ps, float* __restrict__ cost) {
    int bq   = blockIdx.x;         // 0..199
    int b    = bq / Q_;
    int lane = threadIdx.x;        // 64
    if (lane < T_) {
        float S1 = 0.f, S2 = 0.f, F = 0.f, P = 0.f;
        for (int s = 0; s < S2_; ++s) {
            const float* pp = part + ((size_t)s * (B_ * Q_) + bq) * NPART;
            S1 += pp[lane]; S2 += pp[T_ + lane]; F += pp[40]; P += pp[41];
        }
        float L = 0.f;
        for (int sl = 0; sl < S2_; ++sl) L += lab_ps[(b * T_ + lane) * S2_ + sl];
        float cm = (S1 + F) * (1.0f / (float)HW_);
        float cd = 1.0f - (2.0f * S2 + 1.0f) / (P + L + 1.0f);
        cost[bq * T_ + lane] = cm + cd + cc[bq * T_ + lane];
    }
}

// ---------------- fallback: monolithic (round-2 proven) ----------------
__global__ __launch_bounds__(1024) void mask_cost_mono_kernel(
        const float* __restrict__ mq, const float* __restrict__ ml,
        const float* __restrict__ cc, const float* __restrict__ lab_ps,
        float* __restrict__ cost) {
    int bq  = blockIdx.x;
    int b   = bq / Q_;
    int tid = threadIdx.x;
    const float* xb  = mq + (size_t)bq * HW_;
    const float* mlb = ml + (size_t)b * T_ * 262144;
    float s1[T_], s2[T_];
#pragma unroll
    for (int t = 0; t < T_; ++t) { s1[t] = 0.f; s2[t] = 0.f; }
    float F = 0.f, P = 0.f;
    for (int k = tid; k < HW_; k += 1024) {
        int i = k >> 8, j = k & 255;
        float x = xb[k];
        float p = 1.0f / (1.0f + expf(-x));
        float spn = softplusf(-x);
        float spp = softplusf(x);
        float om = 1.0f - p;
        float fp = 0.25f * om * om * spn;
        float fn = 0.75f * p * p * spp;
        F += fn; P += p;
        float diff = fp - fn;
        int off0 = i * 1024 + 2 * j;
#pragma unroll
        for (int t = 0; t < T_; ++t) {
            float lab = mlb[t * 262144 + off0];
            s1[t] = fmaf(diff, lab, s1[t]);
            s2[t] = fmaf(p,    lab, s2[t]);
        }
    }
    __shared__ float sbuf[16][42];
    int wid = tid >> 6, lane = tid & 63;
#pragma unroll
    for (int t = 0; t < T_; ++t) {
        for (int off = 32; off > 0; off >>= 1) {
            s1[t] += __shfl_down(s1[t], off);
            s2[t] += __shfl_down(s2[t], off);
        }
    }
    for (int off = 32; off > 0; off >>= 1) { F += __shfl_down(F, off); P += __shfl_down(P, off); }
    if (lane == 0) {
#pragma unroll
        for (int t = 0; t < T_; ++t) { sbuf[wid][t] = s1[t]; sbuf[wid][T_ + t] = s2[t]; }
        sbuf[wid][40] = F; sbuf[wid][41] = P;
    }
    __syncthreads();
    if (tid < T_) {
        float S1 = 0.f, S2 = 0.f, Fs = 0.f, Ps = 0.f;
        for (int w = 0; w < 16; ++w) {
            S1 += sbuf[w][tid]; S2 += sbuf[w][T_ + tid];
            Fs += sbuf[w][40];  Ps += sbuf[w][41];
        }
        float L = 0.f;
        for (int sl = 0; sl < S2_; ++sl) L += lab_ps[(b * T_ + tid) * S2_ + sl];
        float cm = (S1 + Fs) * (1.0f / (float)HW_);
        float cd = 1.0f - (2.0f * S2 + 1.0f) / (Ps + L + 1.0f);
        cost[bq * T_ + tid] = cm + cd + cc[bq * T_ + tid];
    }
}

// ---------------- K5: transposed rectangular JV Hungarian, one wave ----------------
__global__ __launch_bounds__(64) void hungarian_kernel(const float* __restrict__ cost,
                                                       int* __restrict__ out) {
    int b    = blockIdx.x;
    int lane = threadIdx.x;

    __shared__ float  csh[Q_ * T_];
    __shared__ double u[T_ + 1];
    __shared__ int    p[NHUN + 1];
    __shared__ int    way[NHUN + 1];

    for (int idx = lane; idx < Q_ * T_; idx += 64) csh[idx] = cost[b * Q_ * T_ + idx];
    for (int j = lane; j <= NHUN; j += 64) { p[j] = 0; way[j] = 0; }
    if (lane <= T_) u[lane] = 0.0;
    __syncthreads();

    const int ja = lane;
    const int jb = lane + 64;
    const bool jb_ok = (jb <= NHUN);
    double v_a = 0.0, v_b = 0.0;

    for (int i = 1; i <= T_; ++i) {
        if (lane == 0) p[0] = i;
        double m_a = INFINITY, m_b = INFINITY;
        bool us_a = false, us_b = false;
        __syncthreads();
        int j0 = 0;
        while (true) {
            if (ja == j0) us_a = true;
            if (jb == j0) us_b = true;
            int    i0  = p[j0];
            double ui0 = u[i0];
            double cand = INFINITY; int candj = 0x7fffffff;
            if (!us_a && ja >= 1) {
                double cur = (double)csh[(ja - 1) * T_ + (i0 - 1)] - ui0 - v_a;
                if (cur < m_a) { m_a = cur; way[ja] = j0; }
                cand = m_a; candj = ja;
            }
            if (jb_ok && !us_b) {
                double cur = (double)csh[(jb - 1) * T_ + (i0 - 1)] - ui0 - v_b;
                if (cur < m_b) { m_b = cur; way[jb] = j0; }
                if (m_b < cand || (m_b == cand && jb < candj)) { cand = m_b; candj = jb; }
            }
            for (int off = 32; off > 0; off >>= 1) {
                double ov = __shfl_xor(cand, off);
                int    oj = __shfl_xor(candj, off);
                if (ov < cand || (ov == cand && oj < candj)) { cand = ov; candj = oj; }
            }
            double delta = cand; int j1 = candj;
            if (us_a) { u[p[ja]] += delta; v_a -= delta; } else { m_a -= delta; }
            if (jb_ok) {
                if (us_b) { u[p[jb]] += delta; v_b -= delta; } else { m_b -= delta; }
            }
            j0 = j1;
            __syncthreads();
            if (p[j0] == 0) break;
        }
        if (lane == 0) {
            int jj = j0;
            while (jj) { int jn = way[jj]; p[jj] = p[jn]; jj = jn; }
        }
        __syncthreads();
    }

    if (lane == 0) {
        int* ob = out + b * 2 * T_;
        int k = 0;
        for (int j = 1; j <= NHUN; ++j) {
            if (p[j] != 0) { ob[k] = j - 1; ob[T_ + k] = p[j] - 1; ++k; }
        }
    }
}

extern "C" void kernel_launch(void* const* d_in, const int* in_sizes, int n_in,
                              void* d_out, int out_size, void* d_ws, size_t ws_size,
                              hipStream_t stream) {
    const float* mq     = (const float*)d_in[0];   // [2,100,256,256]
    const float* cl     = (const float*)d_in[1];   // [2,100,134]
    const float* ml     = (const float*)d_in[2];   // [2,20,512,512]
    const int*   labels = (const int*)d_in[3];     // [2,20]
    int* out = (int*)d_out;                        // [2,2,20] int32
    float* ws = (float*)d_ws;

    float* lab_ps = ws + LABPS_OFF;
    float* cc     = ws + CC_OFF;
    float* cost   = ws + COST_OFF;

    size_t need_t1 = (size_t)T1_END * 4;

    if (ws_size >= need_t1) {
        float* labC = ws + LABC_OFF;
        float* part = ws + PART_OFF;
        hipLaunchKernelGGL(lab_prep_kernel,   dim3(B_, S2_),  dim3(256), 0, stream, ml, lab_ps, labC, 1);
        hipLaunchKernelGGL(class_cost_kernel, dim3(B_ * Q_),  dim3(64),  0, stream, cl, labels, cc);
        hipLaunchKernelGGL(focal2_kernel,     dim3(S2_ * B_ * 50), dim3(256), 0, stream, mq, labC, part);
        hipLaunchKernelGGL(compose_kernel,    dim3(B_ * Q_),  dim3(64),  0, stream, part, cc, lab_ps, cost);
    } else {
        hipLaunchKernelGGL(lab_prep_kernel,   dim3(B_, S2_),  dim3(256), 0, stream, ml, lab_ps, ws, 0);
        hipLaunchKernelGGL(class_cost_kernel, dim3(B_ * Q_),  dim3(64),  0, stream, cl, labels, cc);
        hipLaunchKernelGGL(mask_cost_mono_kernel, dim3(B_ * Q_), dim3(1024), 0, stream, mq, ml, cc, lab_ps, cost);
    }
    hipLaunchKernelGGL(hungarian_kernel, dim3(B_), dim3(64), 0, stream, cost, out);
}

// Round 5
// 118.868 us; speedup vs baseline: 1.5006x; 1.5006x over previous
//
#include <hip/hip_runtime.h>
#include <hip/hip_bf16.h>
#include <math.h>

#define HW_   65536
#define B_    2
#define Q_    100
#define C_    134
#define T_    20
#define NHUN  100
#define MT_   7            // M-tiles of 16 queries (112 >= 100)
#define KSB   64           // K-split blocks per (b,mt)
#define BKCH  1024         // k per block
#define WKCH  256          // k per wave (8 MFMA k-steps)

typedef __attribute__((ext_vector_type(8))) short bf16x8;
typedef __attribute__((ext_vector_type(4))) float f32x4;

// ws layout (float units)
#define LABPS_OFF  0                    // [2][20][8]
#define CC_OFF     512                  // [200][20]
#define COST_OFF   4608                 // [200][20]
#define BASE_END   8704
#define LABT_HI_F  BASE_END                         // 2*20*65536 ushort = 1,310,720 floats
#define LABT_LO_F  (LABT_HI_F + 1310720)
#define PART_OFF   (LABT_LO_F + 1310720)            // 896*1536 floats
#define WS_END_F   (PART_OFF + 896 * 1536)

__device__ inline unsigned short f2bf(float f) {
    unsigned int u = __builtin_bit_cast(unsigned int, f);
    u += 0x7FFFu + ((u >> 16) & 1u);               // RNE
    return (unsigned short)(u >> 16);
}
__device__ inline float bf2f(unsigned short h) {
    return __builtin_bit_cast(float, (unsigned int)h << 16);
}
__device__ inline float softplusf(float x) {
    float ax = fabsf(x);
    return fmaxf(x, 0.0f) + log1pf(expf(-ax));
}

// ---------------- K1: decimate labels -> bf16 hi/lo rows [b][t][65536] + row-sum partials ----------------
// grid (B_, T_, 8 k-slices), 256 thr
__global__ void lab_prep_kernel(const float* __restrict__ ml, unsigned short* __restrict__ labT_hi,
                                unsigned short* __restrict__ labT_lo, float* __restrict__ lab_ps,
                                int writeT) {
    int b = blockIdx.x, t = blockIdx.y, ksl = blockIdx.z;
    int tid = threadIdx.x;
    const float* src = ml + (size_t)(b * T_ + t) * 262144;
    size_t dst = ((size_t)(b * T_ + t)) << 16;
    float acc = 0.f;
    for (int it = 0; it < 8; ++it) {
        int k = ksl * 8192 + it * 1024 + tid * 4;
        int r = k >> 8, c = k & 255;
        const float* s = src + r * 1024 + 2 * c;
        float4 u = *(const float4*)s;
        float4 w = *(const float4*)(s + 4);
        float v[4] = {u.x, u.z, w.x, w.z};
        unsigned short h[4], l[4];
#pragma unroll
        for (int e = 0; e < 4; ++e) {
            h[e] = f2bf(v[e]);
            l[e] = f2bf(v[e] - bf2f(h[e]));
            acc += v[e];
        }
        if (writeT) {
            *(ushort4*)(labT_hi + dst + k) = make_ushort4(h[0], h[1], h[2], h[3]);
            *(ushort4*)(labT_lo + dst + k) = make_ushort4(l[0], l[1], l[2], l[3]);
        }
    }
    for (int off = 32; off > 0; off >>= 1) acc += __shfl_down(acc, off);
    __shared__ float sb[4];
    int wid = tid >> 6, lane = tid & 63;
    if (lane == 0) sb[wid] = acc;
    __syncthreads();
    if (tid == 0) lab_ps[(b * T_ + t) * 8 + ksl] = sb[0] + sb[1] + sb[2] + sb[3];
}

// ---------------- K2: class cost ----------------
__global__ void class_cost_kernel(const float* __restrict__ cl, const int* __restrict__ labels,
                                  float* __restrict__ cc) {
    int bq  = blockIdx.x;
    int b   = bq / Q_;
    int tid = threadIdx.x;         // 64
    __shared__ float sl[C_];
    const float* src = cl + (size_t)bq * C_;
    for (int c = tid; c < C_; c += 64) sl[c] = src[c];
    __syncthreads();
    float mx = -INFINITY;
    for (int c = tid; c < C_; c += 64) mx = fmaxf(mx, sl[c]);
    for (int off = 32; off > 0; off >>= 1) mx = fmaxf(mx, __shfl_xor(mx, off));
    float se = 0.f;
    for (int c = tid; c < C_; c += 64) se += expf(sl[c] - mx);
    for (int off = 32; off > 0; off >>= 1) se += __shfl_xor(se, off);
    float inv = 1.0f / se;
    if (tid < T_) {
        int lbl = labels[b * T_ + tid];
        cc[bq * T_ + tid] = -expf(sl[lbl] - mx) * inv;
    }
}

__device__ inline void cvt_hilo(const float* v, bf16x8& hi, bf16x8& lo) {
#pragma unroll
    for (int e = 0; e < 8; ++e) {
        unsigned short h = f2bf(v[e]);
        hi[e] = (short)h;
        lo[e] = (short)f2bf(v[e] - bf2f(h));
    }
}

// ---------------- K3: fused pointwise + MFMA GEMM partials ----------------
// blockIdx.x = (b*KSB + ks)*MT_ + mt ; 256 thr (4 waves, each 256 k)
// C quantities: 0=fp, 1=fn, 2=p ; B cols: n=0..19 lab rows, n=20 ones, n>20 zero
__global__ __launch_bounds__(256) void focal_mfma_kernel(
        const float* __restrict__ mq, const unsigned short* __restrict__ labT_hi,
        const unsigned short* __restrict__ labT_lo, float* __restrict__ part) {
    int idx = blockIdx.x;
    int mt  = idx % MT_;
    int rem = idx / MT_;
    int ks  = rem % KSB;
    int b   = rem / KSB;
    int tid  = threadIdx.x;
    int wave = tid >> 6, lane = tid & 63;
    int lg = lane >> 4, lr = lane & 15;

    int q = mt * 16 + lr;
    bool qok = (q < Q_);
    const float* xrow = mq + ((size_t)(b * Q_ + (qok ? q : 0)) << 16);
    int koff = ks * BKCH + wave * WKCH + lg * 8;   // this lane's k base

    // B row pointers (ntile1: row lr ; ntile2: row 16+lr valid for lr<4, lr==4 ones, lr>4 zero)
    const unsigned short* b1h = labT_hi + (((size_t)(b * T_ + lr)) << 16);
    const unsigned short* b1l = labT_lo + (((size_t)(b * T_ + lr)) << 16);
    const unsigned short* b2h = labT_hi + (((size_t)(b * T_ + 16 + (lr & 3))) << 16);
    const unsigned short* b2l = labT_lo + (((size_t)(b * T_ + 16 + (lr & 3))) << 16);
    bool n2row = (lr < 4);
    bool n2one = (lr == 4);

    f32x4 accA0 = {0,0,0,0}, accA1 = {0,0,0,0};   // fp  x ntile1/2
    f32x4 accB0 = {0,0,0,0}, accB1 = {0,0,0,0};   // fn
    f32x4 accC0 = {0,0,0,0}, accC1 = {0,0,0,0};   // p

    bf16x8 onesh; bf16x8 zer;
#pragma unroll
    for (int e = 0; e < 8; ++e) { onesh[e] = (short)0x3F80; zer[e] = 0; }

    for (int kk = 0; kk < 8; ++kk) {
        int kb = koff + kk * 32;
        float xv[8];
        if (qok) {
            float4 u0 = *(const float4*)(xrow + kb);
            float4 u1 = *(const float4*)(xrow + kb + 4);
            xv[0]=u0.x; xv[1]=u0.y; xv[2]=u0.z; xv[3]=u0.w;
            xv[4]=u1.x; xv[5]=u1.y; xv[6]=u1.z; xv[7]=u1.w;
        } else {
#pragma unroll
            for (int e = 0; e < 8; ++e) xv[e] = 0.f;
        }
        // B frags
        bf16x8 f1h = *(const bf16x8*)(b1h + kb);
        bf16x8 f1l = *(const bf16x8*)(b1l + kb);
        bf16x8 f2h = n2row ? *(const bf16x8*)(b2h + kb) : (n2one ? onesh : zer);
        bf16x8 f2l = n2row ? *(const bf16x8*)(b2l + kb) : zer;

        float fpv[8], fnv[8], pv[8];
#pragma unroll
        for (int e = 0; e < 8; ++e) {
            float x  = xv[e];
            float ax = fabsf(x);
            float a  = __expf(-ax);
            float rr = 1.0f / (1.0f + a);
            float p  = (x >= 0.f) ? rr : a * rr;
            float om = (x >= 0.f) ? a * rr : rr;
            float l1 = __logf(1.0f + a);
            float spn = fmaxf(-x, 0.f) + l1;
            float spp = spn + x;
            fpv[e] = 0.25f * om * om * spn;
            fnv[e] = 0.75f * p * p * spp;
            pv[e]  = p;
        }
        bf16x8 afh, afl, anh, anl, aph, apl;
        cvt_hilo(fpv, afh, afl);
        cvt_hilo(fnv, anh, anl);
        cvt_hilo(pv,  aph, apl);

        // 3-pass hi/lo MFMA per quantity per ntile
        accA0 = __builtin_amdgcn_mfma_f32_16x16x32_bf16(afh, f1h, accA0, 0, 0, 0);
        accA0 = __builtin_amdgcn_mfma_f32_16x16x32_bf16(afh, f1l, accA0, 0, 0, 0);
        accA0 = __builtin_amdgcn_mfma_f32_16x16x32_bf16(afl, f1h, accA0, 0, 0, 0);
        accA1 = __builtin_amdgcn_mfma_f32_16x16x32_bf16(afh, f2h, accA1, 0, 0, 0);
        accA1 = __builtin_amdgcn_mfma_f32_16x16x32_bf16(afh, f2l, accA1, 0, 0, 0);
        accA1 = __builtin_amdgcn_mfma_f32_16x16x32_bf16(afl, f2h, accA1, 0, 0, 0);

        accB0 = __builtin_amdgcn_mfma_f32_16x16x32_bf16(anh, f1h, accB0, 0, 0, 0);
        accB0 = __builtin_amdgcn_mfma_f32_16x16x32_bf16(anh, f1l, accB0, 0, 0, 0);
        accB0 = __builtin_amdgcn_mfma_f32_16x16x32_bf16(anl, f1h, accB0, 0, 0, 0);
        accB1 = __builtin_amdgcn_mfma_f32_16x16x32_bf16(anh, f2h, accB1, 0, 0, 0);
        accB1 = __builtin_amdgcn_mfma_f32_16x16x32_bf16(anh, f2l, accB1, 0, 0, 0);
        accB1 = __builtin_amdgcn_mfma_f32_16x16x32_bf16(anl, f2h, accB1, 0, 0, 0);

        accC0 = __builtin_amdgcn_mfma_f32_16x16x32_bf16(aph, f1h, accC0, 0, 0, 0);
        accC0 = __builtin_amdgcn_mfma_f32_16x16x32_bf16(aph, f1l, accC0, 0, 0, 0);
        accC0 = __builtin_amdgcn_mfma_f32_16x16x32_bf16(apl, f1h, accC0, 0, 0, 0);
        accC1 = __builtin_amdgcn_mfma_f32_16x16x32_bf16(aph, f2h, accC1, 0, 0, 0);
        accC1 = __builtin_amdgcn_mfma_f32_16x16x32_bf16(aph, f2l, accC1, 0, 0, 0);
        accC1 = __builtin_amdgcn_mfma_f32_16x16x32_bf16(apl, f2h, accC1, 0, 0, 0);
    }

    // deterministic block reduction: 4 waves -> part[idx][1536]
    __shared__ float red[4][6][64][4];      // 24 KB
#pragma unroll
    for (int r = 0; r < 4; ++r) {
        red[wave][0][lane][r] = accA0[r];
        red[wave][1][lane][r] = accA1[r];
        red[wave][2][lane][r] = accB0[r];
        red[wave][3][lane][r] = accB1[r];
        red[wave][4][lane][r] = accC0[r];
        red[wave][5][lane][r] = accC1[r];
    }
    __syncthreads();
    for (int e = tid; e < 1536; e += 256) {
        int f  = e >> 8;
        int l2 = (e & 255) >> 2;
        int r  = e & 3;
        float s = red[0][f][l2][r] + red[1][f][l2][r] + red[2][f][l2][r] + red[3][f][l2][r];
        part[(size_t)idx * 1536 + e] = s;
    }
}

// ---------------- K4: compose cost from partials ----------------
// grid 14 = b*MT_+mt, 320 thr ; frag element e = ((qt*2+nt)*64 + lane)*4 + reg
// C/D map: col n = nt*16 + (lane&15), row m = (lane>>4)*4 + reg  [guide m89]
__global__ void compose_kernel(const float* __restrict__ part, const float* __restrict__ cc,
                               const float* __restrict__ lab_ps, float* __restrict__ cost) {
    int bm = blockIdx.x;
    int mt = bm % MT_;
    int b  = bm / MT_;
    int tid = threadIdx.x;     // 320
    __shared__ float C[1536];
    for (int e = tid; e < 1536; e += 320) {
        float s = 0.f;
        for (int ks = 0; ks < KSB; ++ks)
            s += part[(size_t)((b * KSB + ks) * MT_ + mt) * 1536 + e];
        C[e] = s;
    }
    __syncthreads();
    int qm = tid / T_, t = tid % T_;
    int q = mt * 16 + qm;
    if (qm < 16 && q < Q_) {
        auto IDX = [](int qt, int n, int m) {
            int nt = n >> 4;
            int lane = ((m >> 2) << 4) | (n & 15);
            return ((qt * 2 + nt) * 64 + lane) * 4 + (m & 3);
        };
        float Sfp = C[IDX(0, t, qm)];
        float Sfn = C[IDX(1, t, qm)];
        float Sp  = C[IDX(2, t, qm)];
        float F   = C[IDX(1, 20, qm)];
        float P   = C[IDX(2, 20, qm)];
        float L = 0.f;
        for (int s8 = 0; s8 < 8; ++s8) L += lab_ps[(b * T_ + t) * 8 + s8];
        float cm = (Sfp - Sfn + F) * (1.0f / (float)HW_);
        float cd = 1.0f - (2.0f * Sp + 1.0f) / (P + L + 1.0f);
        cost[(b * Q_ + q) * T_ + t] = cm + cd + cc[(b * Q_ + q) * T_ + t];
    }
}

// ---------------- fallback: monolithic (round-2 proven) ----------------
__global__ __launch_bounds__(1024) void mask_cost_mono_kernel(
        const float* __restrict__ mq, const float* __restrict__ ml,
        const float* __restrict__ cc, const float* __restrict__ lab_ps,
        float* __restrict__ cost) {
    int bq  = blockIdx.x;
    int b   = bq / Q_;
    int tid = threadIdx.x;
    const float* xb  = mq + (size_t)bq * HW_;
    const float* mlb = ml + (size_t)b * T_ * 262144;
    float s1[T_], s2[T_];
#pragma unroll
    for (int t = 0; t < T_; ++t) { s1[t] = 0.f; s2[t] = 0.f; }
    float F = 0.f, P = 0.f;
    for (int k = tid; k < HW_; k += 1024) {
        int i = k >> 8, j = k & 255;
        float x = xb[k];
        float p = 1.0f / (1.0f + expf(-x));
        float spn = softplusf(-x);
        float spp = softplusf(x);
        float om = 1.0f - p;
        float fp = 0.25f * om * om * spn;
        float fn = 0.75f * p * p * spp;
        F += fn; P += p;
        float diff = fp - fn;
        int off0 = i * 1024 + 2 * j;
#pragma unroll
        for (int t = 0; t < T_; ++t) {
            float lab = mlb[t * 262144 + off0];
            s1[t] = fmaf(diff, lab, s1[t]);
            s2[t] = fmaf(p,    lab, s2[t]);
        }
    }
    __shared__ float sbuf[16][42];
    int wid = tid >> 6, lane = tid & 63;
#pragma unroll
    for (int t = 0; t < T_; ++t) {
        for (int off = 32; off > 0; off >>= 1) {
            s1[t] += __shfl_down(s1[t], off);
            s2[t] += __shfl_down(s2[t], off);
        }
    }
    for (int off = 32; off > 0; off >>= 1) { F += __shfl_down(F, off); P += __shfl_down(P, off); }
    if (lane == 0) {
#pragma unroll
        for (int t = 0; t < T_; ++t) { sbuf[wid][t] = s1[t]; sbuf[wid][T_ + t] = s2[t]; }
        sbuf[wid][40] = F; sbuf[wid][41] = P;
    }
    __syncthreads();
    if (tid < T_) {
        float S1 = 0.f, S2 = 0.f, Fs = 0.f, Ps = 0.f;
        for (int w = 0; w < 16; ++w) {
            S1 += sbuf[w][tid]; S2 += sbuf[w][T_ + tid];
            Fs += sbuf[w][40];  Ps += sbuf[w][41];
        }
        float L = 0.f;
        for (int sl = 0; sl < 8; ++sl) L += lab_ps[(b * T_ + tid) * 8 + sl];
        float cm = (S1 + Fs) * (1.0f / (float)HW_);
        float cd = 1.0f - (2.0f * S2 + 1.0f) / (Ps + L + 1.0f);
        cost[bq * T_ + tid] = cm + cd + cc[bq * T_ + tid];
    }
}

// ---------------- K5: transposed rectangular JV Hungarian, one wave ----------------
__global__ __launch_bounds__(64) void hungarian_kernel(const float* __restrict__ cost,
                                                       int* __restrict__ out) {
    int b    = blockIdx.x;
    int lane = threadIdx.x;

    __shared__ float  csh[Q_ * T_];
    __shared__ double u[T_ + 1];
    __shared__ int    p[NHUN + 1];
    __shared__ int    way[NHUN + 1];

    for (int idx = lane; idx < Q_ * T_; idx += 64) csh[idx] = cost[b * Q_ * T_ + idx];
    for (int j = lane; j <= NHUN; j += 64) { p[j] = 0; way[j] = 0; }
    if (lane <= T_) u[lane] = 0.0;
    __syncthreads();

    const int ja = lane;
    const int jb = lane + 64;
    const bool jb_ok = (jb <= NHUN);
    double v_a = 0.0, v_b = 0.0;

    for (int i = 1; i <= T_; ++i) {
        if (lane == 0) p[0] = i;
        double m_a = INFINITY, m_b = INFINITY;
        bool us_a = false, us_b = false;
        __syncthreads();
        int j0 = 0;
        while (true) {
            if (ja == j0) us_a = true;
            if (jb == j0) us_b = true;
            int    i0  = p[j0];
            double ui0 = u[i0];
            double cand = INFINITY; int candj = 0x7fffffff;
            if (!us_a && ja >= 1) {
                double cur = (double)csh[(ja - 1) * T_ + (i0 - 1)] - ui0 - v_a;
                if (cur < m_a) { m_a = cur; way[ja] = j0; }
                cand = m_a; candj = ja;
            }
            if (jb_ok && !us_b) {
                double cur = (double)csh[(jb - 1) * T_ + (i0 - 1)] - ui0 - v_b;
                if (cur < m_b) { m_b = cur; way[jb] = j0; }
                if (m_b < cand || (m_b == cand && jb < candj)) { cand = m_b; candj = jb; }
            }
            for (int off = 32; off > 0; off >>= 1) {
                double ov = __shfl_xor(cand, off);
                int    oj = __shfl_xor(candj, off);
                if (ov < cand || (ov == cand && oj < candj)) { cand = ov; candj = oj; }
            }
            double delta = cand; int j1 = candj;
            if (us_a) { u[p[ja]] += delta; v_a -= delta; } else { m_a -= delta; }
            if (jb_ok) {
                if (us_b) { u[p[jb]] += delta; v_b -= delta; } else { m_b -= delta; }
            }
            j0 = j1;
            __syncthreads();
            if (p[j0] == 0) break;
        }
        if (lane == 0) {
            int jj = j0;
            while (jj) { int jn = way[jj]; p[jj] = p[jn]; jj = jn; }
        }
        __syncthreads();
    }

    if (lane == 0) {
        int* ob = out + b * 2 * T_;
        int k = 0;
        for (int j = 1; j <= NHUN; ++j) {
            if (p[j] != 0) { ob[k] = j - 1; ob[T_ + k] = p[j] - 1; ++k; }
        }
    }
}

extern "C" void kernel_launch(void* const* d_in, const int* in_sizes, int n_in,
                              void* d_out, int out_size, void* d_ws, size_t ws_size,
                              hipStream_t stream) {
    const float* mq     = (const float*)d_in[0];   // [2,100,256,256]
    const float* cl     = (const float*)d_in[1];   // [2,100,134]
    const float* ml     = (const float*)d_in[2];   // [2,20,512,512]
    const int*   labels = (const int*)d_in[3];     // [2,20]
    int* out = (int*)d_out;                        // [2,2,20] int32
    float* ws = (float*)d_ws;

    float* lab_ps = ws + LABPS_OFF;
    float* cc     = ws + CC_OFF;
    float* cost   = ws + COST_OFF;

    size_t need = (size_t)WS_END_F * 4;

    if (ws_size >= need) {
        unsigned short* labT_hi = (unsigned short*)(ws + LABT_HI_F);
        unsigned short* labT_lo = (unsigned short*)(ws + LABT_LO_F);
        float* part = ws + PART_OFF;
        hipLaunchKernelGGL(lab_prep_kernel,   dim3(B_, T_, 8), dim3(256), 0, stream,
                           ml, labT_hi, labT_lo, lab_ps, 1);
        hipLaunchKernelGGL(class_cost_kernel, dim3(B_ * Q_),   dim3(64),  0, stream, cl, labels, cc);
        hipLaunchKernelGGL(focal_mfma_kernel, dim3(B_ * KSB * MT_), dim3(256), 0, stream,
                           mq, labT_hi, labT_lo, part);
        hipLaunchKernelGGL(compose_kernel,    dim3(B_ * MT_),  dim3(320), 0, stream,
                           part, cc, lab_ps, cost);
    } else {
        hipLaunchKernelGGL(lab_prep_kernel,   dim3(B_, T_, 8), dim3(256), 0, stream,
                           ml, (unsigned short*)ws, (unsigned short*)ws, lab_ps, 0);
        hipLaunchKernelGGL(class_cost_kernel, dim3(B_ * Q_),   dim3(64),  0, stream, cl, labels, cc);
        hipLaunchKernelGGL(mask_cost_mono_kernel, dim3(B_ * Q_), dim3(1024), 0, stream,
                           mq, ml, cc, lab_ps, cost);
    }
    hipLaunchKernelGGL(hungarian_kernel, dim3(B_), dim3(64), 0, stream, cost, out);
}

// Round 6
// 117.518 us; speedup vs baseline: 1.5178x; 1.0115x over previous
//
#include <hip/hip_runtime.h>
#include <hip/hip_bf16.h>
#include <math.h>

#define HW_   65536
#define B_    2
#define Q_    100
#define C_    134
#define T_    20
#define NHUN  100
#define MT_   7            // M-tiles of 16 queries (112 >= 100)
#define KSB   128          // K-split blocks per (b,mt)
#define BKCH  512          // k per block
#define WKCH  128          // k per wave (4 MFMA k-steps)
#define PREC  1088         // part record stride (1024 frag + 16 F + 16 P + pad)

typedef __attribute__((ext_vector_type(8))) short bf16x8;
typedef __attribute__((ext_vector_type(4))) float f32x4;

// ws layout (float units)
#define LABPS_OFF  0                    // [2][20][8]
#define CC_OFF     512                  // [200][20]
#define COST_OFF   4608                 // [200][20]
#define BASE_END   8704
#define LABT_HI_F  BASE_END                         // 2*20*65536 ushort = 1,310,720 floats
#define PART_OFF   (LABT_HI_F + 1310720)            // 1792 records * 1088 floats
#define WS_END_F   (PART_OFF + B_ * KSB * MT_ * PREC)

__device__ inline unsigned short f2bf(float f) {
    unsigned int u = __builtin_bit_cast(unsigned int, f);
    u += 0x7FFFu + ((u >> 16) & 1u);               // RNE
    return (unsigned short)(u >> 16);
}
__device__ inline float softplusf(float x) {
    float ax = fabsf(x);
    return fmaxf(x, 0.0f) + log1pf(expf(-ax));
}

// ---------------- K1: decimate labels -> bf16 rows [b][t][65536] + row-sum partials ----------------
// grid (B_, T_, 8 k-slices), 256 thr
__global__ void lab_prep_kernel(const float* __restrict__ ml, unsigned short* __restrict__ labT,
                                float* __restrict__ lab_ps, int writeT) {
    int b = blockIdx.x, t = blockIdx.y, ksl = blockIdx.z;
    int tid = threadIdx.x;
    const float* src = ml + (size_t)(b * T_ + t) * 262144;
    size_t dst = ((size_t)(b * T_ + t)) << 16;
    float acc = 0.f;
    for (int it = 0; it < 8; ++it) {
        int k = ksl * 8192 + it * 1024 + tid * 4;
        int r = k >> 8, c = k & 255;
        const float* s = src + r * 1024 + 2 * c;
        float4 u = *(const float4*)s;
        float4 w = *(const float4*)(s + 4);
        float v[4] = {u.x, u.z, w.x, w.z};
        unsigned short h[4];
#pragma unroll
        for (int e = 0; e < 4; ++e) { h[e] = f2bf(v[e]); acc += v[e]; }
        if (writeT) *(ushort4*)(labT + dst + k) = make_ushort4(h[0], h[1], h[2], h[3]);
    }
    for (int off = 32; off > 0; off >>= 1) acc += __shfl_down(acc, off);
    __shared__ float sb[4];
    int wid = tid >> 6, lane = tid & 63;
    if (lane == 0) sb[wid] = acc;
    __syncthreads();
    if (tid == 0) lab_ps[(b * T_ + t) * 8 + ksl] = sb[0] + sb[1] + sb[2] + sb[3];
}

// ---------------- K2: class cost ----------------
__global__ void class_cost_kernel(const float* __restrict__ cl, const int* __restrict__ labels,
                                  float* __restrict__ cc) {
    int bq  = blockIdx.x;
    int b   = bq / Q_;
    int tid = threadIdx.x;         // 64
    __shared__ float sl[C_];
    const float* src = cl + (size_t)bq * C_;
    for (int c = tid; c < C_; c += 64) sl[c] = src[c];
    __syncthreads();
    float mx = -INFINITY;
    for (int c = tid; c < C_; c += 64) mx = fmaxf(mx, sl[c]);
    for (int off = 32; off > 0; off >>= 1) mx = fmaxf(mx, __shfl_xor(mx, off));
    float se = 0.f;
    for (int c = tid; c < C_; c += 64) se += expf(sl[c] - mx);
    for (int off = 32; off > 0; off >>= 1) se += __shfl_xor(se, off);
    float inv = 1.0f / se;
    if (tid < T_) {
        int lbl = labels[b * T_ + tid];
        cc[bq * T_ + tid] = -expf(sl[lbl] - mx) * inv;
    }
}

// ---------------- K3: fused pointwise + single-pass bf16 MFMA partials ----------------
// blockIdx.x = (b*KSB + ks)*MT_ + mt ; 256 thr (4 waves, each 128 k)
// MFMA quantities: d = fp-fn, p ; F=sum fn, P=sum p via scalar f32 accumulators
__global__ __launch_bounds__(256) void focal_mfma_kernel(
        const float* __restrict__ mq, const unsigned short* __restrict__ labT,
        float* __restrict__ part) {
    int idx = blockIdx.x;
    int mt  = idx % MT_;
    int rem = idx / MT_;
    int ks  = rem % KSB;
    int b   = rem / KSB;
    int tid  = threadIdx.x;
    int wave = tid >> 6, lane = tid & 63;
    int lg = lane >> 4, lr = lane & 15;

    int q = mt * 16 + lr;
    bool qok = (q < Q_);
    const float* xrow = mq + ((size_t)(b * Q_ + (qok ? q : 0)) << 16);
    int koff = ks * BKCH + wave * WKCH + lg * 8;   // this lane's k base

    const unsigned short* b1 = labT + (((size_t)(b * T_ + lr)) << 16);
    const unsigned short* b2 = labT + (((size_t)(b * T_ + 16 + (lr & 3))) << 16);
    bool n2row = (lr < 4);

    f32x4 accD0 = {0,0,0,0}, accD1 = {0,0,0,0};   // d x ntile1/2
    f32x4 accP0 = {0,0,0,0}, accP1 = {0,0,0,0};   // p
    float F = 0.f, P = 0.f;

    bf16x8 zer;
#pragma unroll
    for (int e = 0; e < 8; ++e) zer[e] = 0;

    for (int kk = 0; kk < 4; ++kk) {
        int kb = koff + kk * 32;
        float4 u0 = *(const float4*)(xrow + kb);
        float4 u1 = *(const float4*)(xrow + kb + 4);
        float xv[8] = {u0.x, u0.y, u0.z, u0.w, u1.x, u1.y, u1.z, u1.w};

        bf16x8 f1 = *(const bf16x8*)(b1 + kb);
        bf16x8 f2 = n2row ? *(const bf16x8*)(b2 + kb) : zer;

        bf16x8 dh, ph;
#pragma unroll
        for (int e = 0; e < 8; ++e) {
            float x  = xv[e];
            float ax = fabsf(x);
            float a  = __expf(-ax);
            float rr = 1.0f / (1.0f + a);
            float p  = (x >= 0.f) ? rr : a * rr;
            float om = (x >= 0.f) ? a * rr : rr;
            float l1 = __logf(1.0f + a);
            float spn = fmaxf(-x, 0.f) + l1;       // softplus(-x)
            float spp = spn + x;                   // softplus(x)
            float fp = 0.25f * om * om * spn;
            float fn = 0.75f * p * p * spp;
            F += fn; P += p;
            dh[e] = (short)f2bf(fp - fn);
            ph[e] = (short)f2bf(p);
        }
        accD0 = __builtin_amdgcn_mfma_f32_16x16x32_bf16(dh, f1, accD0, 0, 0, 0);
        accD1 = __builtin_amdgcn_mfma_f32_16x16x32_bf16(dh, f2, accD1, 0, 0, 0);
        accP0 = __builtin_amdgcn_mfma_f32_16x16x32_bf16(ph, f1, accP0, 0, 0, 0);
        accP1 = __builtin_amdgcn_mfma_f32_16x16x32_bf16(ph, f2, accP1, 0, 0, 0);
    }

    // reduce F,P over the 4 lane-groups (same lr): lanes 0..15 end with totals
    F += __shfl_down(F, 32); F += __shfl_down(F, 16);
    P += __shfl_down(P, 32); P += __shfl_down(P, 16);

    // deterministic block reduction
    __shared__ float red[4][4][64][4];      // 16 KB
    __shared__ float fpb[4][2][16];
#pragma unroll
    for (int r = 0; r < 4; ++r) {
        red[wave][0][lane][r] = accD0[r];
        red[wave][1][lane][r] = accD1[r];
        red[wave][2][lane][r] = accP0[r];
        red[wave][3][lane][r] = accP1[r];
    }
    if (lane < 16) { fpb[wave][0][lane] = F; fpb[wave][1][lane] = P; }
    __syncthreads();
    for (int e = tid; e < 1024; e += 256) {
        int f  = e >> 8;
        int l2 = (e & 255) >> 2;
        int r  = e & 3;
        part[(size_t)idx * PREC + e] =
            red[0][f][l2][r] + red[1][f][l2][r] + red[2][f][l2][r] + red[3][f][l2][r];
    }
    if (tid < 16)
        part[(size_t)idx * PREC + 1024 + tid] =
            fpb[0][0][tid] + fpb[1][0][tid] + fpb[2][0][tid] + fpb[3][0][tid];
    else if (tid < 32) {
        int l = tid - 16;
        part[(size_t)idx * PREC + 1040 + l] =
            fpb[0][1][l] + fpb[1][1][l] + fpb[2][1][l] + fpb[3][1][l];
    }
}

// ---------------- K4: compose cost from partials ----------------
// grid 14 = b*MT_+mt, 320 thr
// C/D map: col n = lane&15, row m = (lane>>4)*4 + reg  [verified R5]
__global__ void compose_kernel(const float* __restrict__ part, const float* __restrict__ cc,
                               const float* __restrict__ lab_ps, float* __restrict__ cost) {
    int bm = blockIdx.x;
    int mt = bm % MT_;
    int b  = bm / MT_;
    int tid = threadIdx.x;     // 320
    __shared__ float C[1056];
    for (int e = tid; e < 1056; e += 320) {
        float s = 0.f;
        for (int ks = 0; ks < KSB; ++ks)
            s += part[(size_t)((b * KSB + ks) * MT_ + mt) * PREC + e];
        C[e] = s;
    }
    __syncthreads();
    int qm = tid / T_, t = tid % T_;
    int q = mt * 16 + qm;
    if (qm < 16 && q < Q_) {
        int nt   = t >> 4;
        int lane = ((qm >> 2) << 4) | (t & 15);
        int reg  = qm & 3;
        float Sd = C[(0 + nt) * 256 + lane * 4 + reg];
        float Sp = C[(2 + nt) * 256 + lane * 4 + reg];
        float F  = C[1024 + qm];
        float P  = C[1040 + qm];
        float L = 0.f;
        for (int s8 = 0; s8 < 8; ++s8) L += lab_ps[(b * T_ + t) * 8 + s8];
        float cm = (Sd + F) * (1.0f / (float)HW_);
        float cd = 1.0f - (2.0f * Sp + 1.0f) / (P + L + 1.0f);
        cost[(b * Q_ + q) * T_ + t] = cm + cd + cc[(b * Q_ + q) * T_ + t];
    }
}

// ---------------- fallback: monolithic (round-2 proven) ----------------
__global__ __launch_bounds__(1024) void mask_cost_mono_kernel(
        const float* __restrict__ mq, const float* __restrict__ ml,
        const float* __restrict__ cc, const float* __restrict__ lab_ps,
        float* __restrict__ cost) {
    int bq  = blockIdx.x;
    int b   = bq / Q_;
    int tid = threadIdx.x;
    const float* xb  = mq + (size_t)bq * HW_;
    const float* mlb = ml + (size_t)b * T_ * 262144;
    float s1[T_], s2[T_];
#pragma unroll
    for (int t = 0; t < T_; ++t) { s1[t] = 0.f; s2[t] = 0.f; }
    float F = 0.f, P = 0.f;
    for (int k = tid; k < HW_; k += 1024) {
        int i = k >> 8, j = k & 255;
        float x = xb[k];
        float p = 1.0f / (1.0f + expf(-x));
        float spn = softplusf(-x);
        float spp = softplusf(x);
        float om = 1.0f - p;
        float fp = 0.25f * om * om * spn;
        float fn = 0.75f * p * p * spp;
        F += fn; P += p;
        float diff = fp - fn;
        int off0 = i * 1024 + 2 * j;
#pragma unroll
        for (int t = 0; t < T_; ++t) {
            float lab = mlb[t * 262144 + off0];
            s1[t] = fmaf(diff, lab, s1[t]);
            s2[t] = fmaf(p,    lab, s2[t]);
        }
    }
    __shared__ float sbuf[16][42];
    int wid = tid >> 6, lane = tid & 63;
#pragma unroll
    for (int t = 0; t < T_; ++t) {
        for (int off = 32; off > 0; off >>= 1) {
            s1[t] += __shfl_down(s1[t], off);
            s2[t] += __shfl_down(s2[t], off);
        }
    }
    for (int off = 32; off > 0; off >>= 1) { F += __shfl_down(F, off); P += __shfl_down(P, off); }
    if (lane == 0) {
#pragma unroll
        for (int t = 0; t < T_; ++t) { sbuf[wid][t] = s1[t]; sbuf[wid][T_ + t] = s2[t]; }
        sbuf[wid][40] = F; sbuf[wid][41] = P;
    }
    __syncthreads();
    if (tid < T_) {
        float S1 = 0.f, S2 = 0.f, Fs = 0.f, Ps = 0.f;
        for (int w = 0; w < 16; ++w) {
            S1 += sbuf[w][tid]; S2 += sbuf[w][T_ + tid];
            Fs += sbuf[w][40];  Ps += sbuf[w][41];
        }
        float L = 0.f;
        for (int sl = 0; sl < 8; ++sl) L += lab_ps[(b * T_ + tid) * 8 + sl];
        float cm = (S1 + Fs) * (1.0f / (float)HW_);
        float cd = 1.0f - (2.0f * S2 + 1.0f) / (Ps + L + 1.0f);
        cost[bq * T_ + tid] = cm + cd + cc[bq * T_ + tid];
    }
}

// ---------------- K5: transposed rectangular JV Hungarian, one wave ----------------
__global__ __launch_bounds__(64) void hungarian_kernel(const float* __restrict__ cost,
                                                       int* __restrict__ out) {
    int b    = blockIdx.x;
    int lane = threadIdx.x;

    __shared__ float  csh[Q_ * T_];
    __shared__ double u[T_ + 1];
    __shared__ int    p[NHUN + 1];
    __shared__ int    way[NHUN + 1];

    for (int idx = lane; idx < Q_ * T_; idx += 64) csh[idx] = cost[b * Q_ * T_ + idx];
    for (int j = lane; j <= NHUN; j += 64) { p[j] = 0; way[j] = 0; }
    if (lane <= T_) u[lane] = 0.0;
    __syncthreads();

    const int ja = lane;
    const int jb = lane + 64;
    const bool jb_ok = (jb <= NHUN);
    double v_a = 0.0, v_b = 0.0;

    for (int i = 1; i <= T_; ++i) {
        if (lane == 0) p[0] = i;
        double m_a = INFINITY, m_b = INFINITY;
        bool us_a = false, us_b = false;
        __syncthreads();
        int j0 = 0;
        while (true) {
            if (ja == j0) us_a = true;
            if (jb == j0) us_b = true;
            int    i0  = p[j0];
            double ui0 = u[i0];
            double cand = INFINITY; int candj = 0x7fffffff;
            if (!us_a && ja >= 1) {
                double cur = (double)csh[(ja - 1) * T_ + (i0 - 1)] - ui0 - v_a;
                if (cur < m_a) { m_a = cur; way[ja] = j0; }
                cand = m_a; candj = ja;
            }
            if (jb_ok && !us_b) {
                double cur = (double)csh[(jb - 1) * T_ + (i0 - 1)] - ui0 - v_b;
                if (cur < m_b) { m_b = cur; way[jb] = j0; }
                if (m_b < cand || (m_b == cand && jb < candj)) { cand = m_b; candj = jb; }
            }
            for (int off = 32; off > 0; off >>= 1) {
                double ov = __shfl_xor(cand, off);
                int    oj = __shfl_xor(candj, off);
                if (ov < cand || (ov == cand && oj < candj)) { cand = ov; candj = oj; }
            }
            double delta = cand; int j1 = candj;
            if (us_a) { u[p[ja]] += delta; v_a -= delta; } else { m_a -= delta; }
            if (jb_ok) {
                if (us_b) { u[p[jb]] += delta; v_b -= delta; } else { m_b -= delta; }
            }
            j0 = j1;
            __syncthreads();
            if (p[j0] == 0) break;
        }
        if (lane == 0) {
            int jj = j0;
            while (jj) { int jn = way[jj]; p[jj] = p[jn]; jj = jn; }
        }
        __syncthreads();
    }

    if (lane == 0) {
        int* ob = out + b * 2 * T_;
        int k = 0;
        for (int j = 1; j <= NHUN; ++j) {
            if (p[j] != 0) { ob[k] = j - 1; ob[T_ + k] = p[j] - 1; ++k; }
        }
    }
}

extern "C" void kernel_launch(void* const* d_in, const int* in_sizes, int n_in,
                              void* d_out, int out_size, void* d_ws, size_t ws_size,
                              hipStream_t stream) {
    const float* mq     = (const float*)d_in[0];   // [2,100,256,256]
    const float* cl     = (const float*)d_in[1];   // [2,100,134]
    const float* ml     = (const float*)d_in[2];   // [2,20,512,512]
    const int*   labels = (const int*)d_in[3];     // [2,20]
    int* out = (int*)d_out;                        // [2,2,20] int32
    float* ws = (float*)d_ws;

    float* lab_ps = ws + LABPS_OFF;
    float* cc     = ws + CC_OFF;
    float* cost   = ws + COST_OFF;

    size_t need = (size_t)WS_END_F * 4;

    if (ws_size >= need) {
        unsigned short* labT = (unsigned short*)(ws + LABT_HI_F);
        float* part = ws + PART_OFF;
        hipLaunchKernelGGL(lab_prep_kernel,   dim3(B_, T_, 8), dim3(256), 0, stream,
                           ml, labT, lab_ps, 1);
        hipLaunchKernelGGL(class_cost_kernel, dim3(B_ * Q_),   dim3(64),  0, stream, cl, labels, cc);
        hipLaunchKernelGGL(focal_mfma_kernel, dim3(B_ * KSB * MT_), dim3(256), 0, stream,
                           mq, labT, part);
        hipLaunchKernelGGL(compose_kernel,    dim3(B_ * MT_),  dim3(320), 0, stream,
                           part, cc, lab_ps, cost);
    } else {
        hipLaunchKernelGGL(lab_prep_kernel,   dim3(B_, T_, 8), dim3(256), 0, stream,
                           ml, (unsigned short*)ws, lab_ps, 0);
        hipLaunchKernelGGL(class_cost_kernel, dim3(B_ * Q_),   dim3(64),  0, stream, cl, labels, cc);
        hipLaunchKernelGGL(mask_cost_mono_kernel, dim3(B_ * Q_), dim3(1024), 0, stream,
                           mq, ml, cc, lab_ps, cost);
    }
    hipLaunchKernelGGL(hungarian_kernel, dim3(B_), dim3(64), 0, stream, cost, out);
}

// Round 7
// 79.067 us; speedup vs baseline: 2.2559x; 1.4863x over previous
//
#include <hip/hip_runtime.h>
#include <hip/hip_bf16.h>
#include <math.h>

#define HW_   65536
#define B_    2
#define Q_    100
#define C_    134
#define T_    20
#define NHUN  100
#define MT_   7            // M-tiles of 16 queries (112 >= 100)
#define KSB   128          // K-split blocks per (b,mt)
#define BKCH  512          // k per block
#define WKCH  128          // k per wave (4 MFMA k-steps)
#define PREC  1088         // part record stride (1024 frag + 16 F + 16 P + pad)

typedef __attribute__((ext_vector_type(8))) short bf16x8;
typedef __attribute__((ext_vector_type(4))) float f32x4;

// ws layout (float units)
#define LABPS_OFF  0                    // [2][20][8]
#define CC_OFF     512                  // [200][20]
#define COST_OFF   4608                 // [200][20]
#define BASE_END   8704
#define LABT_HI_F  BASE_END                         // 2*20*65536 ushort = 1,310,720 floats
#define PART_OFF   (LABT_HI_F + 1310720)            // 1792 records * 1088 floats
#define CSUM_OFF   (PART_OFF + B_ * KSB * MT_ * PREC)   // 14*1056
#define WS_END_F   (CSUM_OFF + B_ * MT_ * 1056)

__device__ inline unsigned short f2bf(float f) {
    unsigned int u = __builtin_bit_cast(unsigned int, f);
    u += 0x7FFFu + ((u >> 16) & 1u);               // RNE
    return (unsigned short)(u >> 16);
}
__device__ inline float softplusf(float x) {
    float ax = fabsf(x);
    return fmaxf(x, 0.0f) + log1pf(expf(-ax));
}

// ---------------- K1: decimate labels -> bf16 rows [b][t][65536] + row-sum partials ----------------
__global__ void lab_prep_kernel(const float* __restrict__ ml, unsigned short* __restrict__ labT,
                                float* __restrict__ lab_ps, int writeT) {
    int b = blockIdx.x, t = blockIdx.y, ksl = blockIdx.z;
    int tid = threadIdx.x;
    const float* src = ml + (size_t)(b * T_ + t) * 262144;
    size_t dst = ((size_t)(b * T_ + t)) << 16;
    float acc = 0.f;
    for (int it = 0; it < 8; ++it) {
        int k = ksl * 8192 + it * 1024 + tid * 4;
        int r = k >> 8, c = k & 255;
        const float* s = src + r * 1024 + 2 * c;
        float4 u = *(const float4*)s;
        float4 w = *(const float4*)(s + 4);
        float v[4] = {u.x, u.z, w.x, w.z};
        unsigned short h[4];
#pragma unroll
        for (int e = 0; e < 4; ++e) { h[e] = f2bf(v[e]); acc += v[e]; }
        if (writeT) *(ushort4*)(labT + dst + k) = make_ushort4(h[0], h[1], h[2], h[3]);
    }
    for (int off = 32; off > 0; off >>= 1) acc += __shfl_down(acc, off);
    __shared__ float sb[4];
    int wid = tid >> 6, lane = tid & 63;
    if (lane == 0) sb[wid] = acc;
    __syncthreads();
    if (tid == 0) lab_ps[(b * T_ + t) * 8 + ksl] = sb[0] + sb[1] + sb[2] + sb[3];
}

// ---------------- K2: class cost ----------------
__global__ void class_cost_kernel(const float* __restrict__ cl, const int* __restrict__ labels,
                                  float* __restrict__ cc) {
    int bq  = blockIdx.x;
    int b   = bq / Q_;
    int tid = threadIdx.x;         // 64
    __shared__ float sl[C_];
    const float* src = cl + (size_t)bq * C_;
    for (int c = tid; c < C_; c += 64) sl[c] = src[c];
    __syncthreads();
    float mx = -INFINITY;
    for (int c = tid; c < C_; c += 64) mx = fmaxf(mx, sl[c]);
    for (int off = 32; off > 0; off >>= 1) mx = fmaxf(mx, __shfl_xor(mx, off));
    float se = 0.f;
    for (int c = tid; c < C_; c += 64) se += expf(sl[c] - mx);
    for (int off = 32; off > 0; off >>= 1) se += __shfl_xor(se, off);
    float inv = 1.0f / se;
    if (tid < T_) {
        int lbl = labels[b * T_ + tid];
        cc[bq * T_ + tid] = -expf(sl[lbl] - mx) * inv;
    }
}

// ---------------- K3: fused pointwise + single-pass bf16 MFMA partials ----------------
__global__ __launch_bounds__(256) void focal_mfma_kernel(
        const float* __restrict__ mq, const unsigned short* __restrict__ labT,
        float* __restrict__ part) {
    int idx = blockIdx.x;
    int mt  = idx % MT_;
    int rem = idx / MT_;
    int ks  = rem % KSB;
    int b   = rem / KSB;
    int tid  = threadIdx.x;
    int wave = tid >> 6, lane = tid & 63;
    int lg = lane >> 4, lr = lane & 15;

    int q = mt * 16 + lr;
    bool qok = (q < Q_);
    const float* xrow = mq + ((size_t)(b * Q_ + (qok ? q : 0)) << 16);
    int koff = ks * BKCH + wave * WKCH + lg * 8;

    const unsigned short* b1 = labT + (((size_t)(b * T_ + lr)) << 16);
    const unsigned short* b2 = labT + (((size_t)(b * T_ + 16 + (lr & 3))) << 16);
    bool n2row = (lr < 4);

    f32x4 accD0 = {0,0,0,0}, accD1 = {0,0,0,0};
    f32x4 accP0 = {0,0,0,0}, accP1 = {0,0,0,0};
    float F = 0.f, P = 0.f;

    bf16x8 zer;
#pragma unroll
    for (int e = 0; e < 8; ++e) zer[e] = 0;

    for (int kk = 0; kk < 4; ++kk) {
        int kb = koff + kk * 32;
        float4 u0 = *(const float4*)(xrow + kb);
        float4 u1 = *(const float4*)(xrow + kb + 4);
        float xv[8] = {u0.x, u0.y, u0.z, u0.w, u1.x, u1.y, u1.z, u1.w};

        bf16x8 f1 = *(const bf16x8*)(b1 + kb);
        bf16x8 f2 = n2row ? *(const bf16x8*)(b2 + kb) : zer;

        bf16x8 dh, ph;
#pragma unroll
        for (int e = 0; e < 8; ++e) {
            float x  = xv[e];
            float ax = fabsf(x);
            float a  = __expf(-ax);
            float rr = 1.0f / (1.0f + a);
            float p  = (x >= 0.f) ? rr : a * rr;
            float om = (x >= 0.f) ? a * rr : rr;
            float l1 = __logf(1.0f + a);
            float spn = fmaxf(-x, 0.f) + l1;
            float spp = spn + x;
            float fp = 0.25f * om * om * spn;
            float fn = 0.75f * p * p * spp;
            F += fn; P += p;
            dh[e] = (short)f2bf(fp - fn);
            ph[e] = (short)f2bf(p);
        }
        accD0 = __builtin_amdgcn_mfma_f32_16x16x32_bf16(dh, f1, accD0, 0, 0, 0);
        accD1 = __builtin_amdgcn_mfma_f32_16x16x32_bf16(dh, f2, accD1, 0, 0, 0);
        accP0 = __builtin_amdgcn_mfma_f32_16x16x32_bf16(ph, f1, accP0, 0, 0, 0);
        accP1 = __builtin_amdgcn_mfma_f32_16x16x32_bf16(ph, f2, accP1, 0, 0, 0);
    }

    F += __shfl_down(F, 32); F += __shfl_down(F, 16);
    P += __shfl_down(P, 32); P += __shfl_down(P, 16);

    __shared__ float red[4][4][64][4];
    __shared__ float fpb[4][2][16];
#pragma unroll
    for (int r = 0; r < 4; ++r) {
        red[wave][0][lane][r] = accD0[r];
        red[wave][1][lane][r] = accD1[r];
        red[wave][2][lane][r] = accP0[r];
        red[wave][3][lane][r] = accP1[r];
    }
    if (lane < 16) { fpb[wave][0][lane] = F; fpb[wave][1][lane] = P; }
    __syncthreads();
    for (int e = tid; e < 1024; e += 256) {
        int f  = e >> 8;
        int l2 = (e & 255) >> 2;
        int r  = e & 3;
        part[(size_t)idx * PREC + e] =
            red[0][f][l2][r] + red[1][f][l2][r] + red[2][f][l2][r] + red[3][f][l2][r];
    }
    if (tid < 16)
        part[(size_t)idx * PREC + 1024 + tid] =
            fpb[0][0][tid] + fpb[1][0][tid] + fpb[2][0][tid] + fpb[3][0][tid];
    else if (tid < 32) {
        int l = tid - 16;
        part[(size_t)idx * PREC + 1040 + l] =
            fpb[0][1][l] + fpb[1][1][l] + fpb[2][1][l] + fpb[3][1][l];
    }
}

// ---------------- K4a: parallel K-split reduction: part[1792][1056] -> Csum[14][1056] ----------------
// grid (14, 33), 256 thr = 32 e-pos x 8 ks-groups; each thread sums 16 records.
__global__ __launch_bounds__(256) void reduce_part_kernel(const float* __restrict__ part,
                                                          float* __restrict__ Csum) {
    int bm   = blockIdx.x;          // 0..13 (b*MT_+mt)
    int mt   = bm % MT_;
    int b    = bm / MT_;
    int tid  = threadIdx.x;
    int epos = tid & 31;
    int grp  = tid >> 5;            // 0..7
    int e    = blockIdx.y * 32 + epos;   // 0..1055

    const float* base = part + (size_t)((b * KSB) * MT_ + mt) * PREC + e;
    float s = 0.f;
    for (int k = 0; k < 16; ++k) {
        s += base[(size_t)(grp * 16 + k) * MT_ * PREC];
    }
    __shared__ float red[8][33];
    red[grp][epos] = s;
    __syncthreads();
    if (tid < 32) {
        float tot = 0.f;
        for (int g = 0; g < 8; ++g) tot += red[g][tid];
        Csum[(size_t)bm * 1056 + e] = tot;
    }
}

// ---------------- K4b: finalize cost from Csum ----------------
// grid 14, 320 thr; C/D map: col n = lane&15, row m = (lane>>4)*4 + reg
__global__ void compose_kernel(const float* __restrict__ Csum, const float* __restrict__ cc,
                               const float* __restrict__ lab_ps, float* __restrict__ cost) {
    int bm = blockIdx.x;
    int mt = bm % MT_;
    int b  = bm / MT_;
    int tid = threadIdx.x;     // 320
    const float* C = Csum + (size_t)bm * 1056;
    int qm = tid / T_, t = tid % T_;
    int q = mt * 16 + qm;
    if (qm < 16 && q < Q_) {
        int nt   = t >> 4;
        int lane = ((qm >> 2) << 4) | (t & 15);
        int reg  = qm & 3;
        float Sd = C[(0 + nt) * 256 + lane * 4 + reg];
        float Sp = C[(2 + nt) * 256 + lane * 4 + reg];
        float F  = C[1024 + qm];
        float P  = C[1040 + qm];
        float L = 0.f;
        for (int s8 = 0; s8 < 8; ++s8) L += lab_ps[(b * T_ + t) * 8 + s8];
        float cm = (Sd + F) * (1.0f / (float)HW_);
        float cd = 1.0f - (2.0f * Sp + 1.0f) / (P + L + 1.0f);
        cost[(b * Q_ + q) * T_ + t] = cm + cd + cc[(b * Q_ + q) * T_ + t];
    }
}

// ---------------- fallback: monolithic (round-2 proven) ----------------
__global__ __launch_bounds__(1024) void mask_cost_mono_kernel(
        const float* __restrict__ mq, const float* __restrict__ ml,
        const float* __restrict__ cc, const float* __restrict__ lab_ps,
        float* __restrict__ cost) {
    int bq  = blockIdx.x;
    int b   = bq / Q_;
    int tid = threadIdx.x;
    const float* xb  = mq + (size_t)bq * HW_;
    const float* mlb = ml + (size_t)b * T_ * 262144;
    float s1[T_], s2[T_];
#pragma unroll
    for (int t = 0; t < T_; ++t) { s1[t] = 0.f; s2[t] = 0.f; }
    float F = 0.f, P = 0.f;
    for (int k = tid; k < HW_; k += 1024) {
        int i = k >> 8, j = k & 255;
        float x = xb[k];
        float p = 1.0f / (1.0f + expf(-x));
        float spn = softplusf(-x);
        float spp = softplusf(x);
        float om = 1.0f - p;
        float fp = 0.25f * om * om * spn;
        float fn = 0.75f * p * p * spp;
        F += fn; P += p;
        float diff = fp - fn;
        int off0 = i * 1024 + 2 * j;
#pragma unroll
        for (int t = 0; t < T_; ++t) {
            float lab = mlb[t * 262144 + off0];
            s1[t] = fmaf(diff, lab, s1[t]);
            s2[t] = fmaf(p,    lab, s2[t]);
        }
    }
    __shared__ float sbuf[16][42];
    int wid = tid >> 6, lane = tid & 63;
#pragma unroll
    for (int t = 0; t < T_; ++t) {
        for (int off = 32; off > 0; off >>= 1) {
            s1[t] += __shfl_down(s1[t], off);
            s2[t] += __shfl_down(s2[t], off);
        }
    }
    for (int off = 32; off > 0; off >>= 1) { F += __shfl_down(F, off); P += __shfl_down(P, off); }
    if (lane == 0) {
#pragma unroll
        for (int t = 0; t < T_; ++t) { sbuf[wid][t] = s1[t]; sbuf[wid][T_ + t] = s2[t]; }
        sbuf[wid][40] = F; sbuf[wid][41] = P;
    }
    __syncthreads();
    if (tid < T_) {
        float S1 = 0.f, S2 = 0.f, Fs = 0.f, Ps = 0.f;
        for (int w = 0; w < 16; ++w) {
            S1 += sbuf[w][tid]; S2 += sbuf[w][T_ + tid];
            Fs += sbuf[w][40];  Ps += sbuf[w][41];
        }
        float L = 0.f;
        for (int sl = 0; sl < 8; ++sl) L += lab_ps[(b * T_ + tid) * 8 + sl];
        float cm = (S1 + Fs) * (1.0f / (float)HW_);
        float cd = 1.0f - (2.0f * S2 + 1.0f) / (Ps + L + 1.0f);
        cost[bq * T_ + tid] = cm + cd + cc[bq * T_ + tid];
    }
}

// ---------------- K5: transposed rectangular JV Hungarian, one wave ----------------
__global__ __launch_bounds__(64) void hungarian_kernel(const float* __restrict__ cost,
                                                       int* __restrict__ out) {
    int b    = blockIdx.x;
    int lane = threadIdx.x;

    __shared__ float  csh[Q_ * T_];
    __shared__ double u[T_ + 1];
    __shared__ int    p[NHUN + 1];
    __shared__ int    way[NHUN + 1];

    for (int idx = lane; idx < Q_ * T_; idx += 64) csh[idx] = cost[b * Q_ * T_ + idx];
    for (int j = lane; j <= NHUN; j += 64) { p[j] = 0; way[j] = 0; }
    if (lane <= T_) u[lane] = 0.0;
    __syncthreads();

    const int ja = lane;
    const int jb = lane + 64;
    const bool jb_ok = (jb <= NHUN);
    double v_a = 0.0, v_b = 0.0;

    for (int i = 1; i <= T_; ++i) {
        if (lane == 0) p[0] = i;
        double m_a = INFINITY, m_b = INFINITY;
        bool us_a = false, us_b = false;
        __syncthreads();
        int j0 = 0;
        while (true) {
            if (ja == j0) us_a = true;
            if (jb == j0) us_b = true;
            int    i0  = p[j0];
            double ui0 = u[i0];
            double cand = INFINITY; int candj = 0x7fffffff;
            if (!us_a && ja >= 1) {
                double cur = (double)csh[(ja - 1) * T_ + (i0 - 1)] - ui0 - v_a;
                if (cur < m_a) { m_a = cur; way[ja] = j0; }
                cand = m_a; candj = ja;
            }
            if (jb_ok && !us_b) {
                double cur = (double)csh[(jb - 1) * T_ + (i0 - 1)] - ui0 - v_b;
                if (cur < m_b) { m_b = cur; way[jb] = j0; }
                if (m_b < cand || (m_b == cand && jb < candj)) { cand = m_b; candj = jb; }
            }
            for (int off = 32; off > 0; off >>= 1) {
                double ov = __shfl_xor(cand, off);
                int    oj = __shfl_xor(candj, off);
                if (ov < cand || (ov == cand && oj < candj)) { cand = ov; candj = oj; }
            }
            double delta = cand; int j1 = candj;
            if (us_a) { u[p[ja]] += delta; v_a -= delta; } else { m_a -= delta; }
            if (jb_ok) {
                if (us_b) { u[p[jb]] += delta; v_b -= delta; } else { m_b -= delta; }
            }
            j0 = j1;
            __syncthreads();
            if (p[j0] == 0) break;
        }
        if (lane == 0) {
            int jj = j0;
            while (jj) { int jn = way[jj]; p[jj] = p[jn]; jj = jn; }
        }
        __syncthreads();
    }

    if (lane == 0) {
        int* ob = out + b * 2 * T_;
        int k = 0;
        for (int j = 1; j <= NHUN; ++j) {
            if (p[j] != 0) { ob[k] = j - 1; ob[T_ + k] = p[j] - 1; ++k; }
        }
    }
}

extern "C" void kernel_launch(void* const* d_in, const int* in_sizes, int n_in,
                              void* d_out, int out_size, void* d_ws, size_t ws_size,
                              hipStream_t stream) {
    const float* mq     = (const float*)d_in[0];   // [2,100,256,256]
    const float* cl     = (const float*)d_in[1];   // [2,100,134]
    const float* ml     = (const float*)d_in[2];   // [2,20,512,512]
    const int*   labels = (const int*)d_in[3];     // [2,20]
    int* out = (int*)d_out;                        // [2,2,20] int32
    float* ws = (float*)d_ws;

    float* lab_ps = ws + LABPS_OFF;
    float* cc     = ws + CC_OFF;
    float* cost   = ws + COST_OFF;

    size_t need = (size_t)WS_END_F * 4;

    if (ws_size >= need) {
        unsigned short* labT = (unsigned short*)(ws + LABT_HI_F);
        float* part = ws + PART_OFF;
        float* Csum = ws + CSUM_OFF;
        hipLaunchKernelGGL(lab_prep_kernel,   dim3(B_, T_, 8), dim3(256), 0, stream,
                           ml, labT, lab_ps, 1);
        hipLaunchKernelGGL(class_cost_kernel, dim3(B_ * Q_),   dim3(64),  0, stream, cl, labels, cc);
        hipLaunchKernelGGL(focal_mfma_kernel, dim3(B_ * KSB * MT_), dim3(256), 0, stream,
                           mq, labT, part);
        hipLaunchKernelGGL(reduce_part_kernel, dim3(B_ * MT_, 33), dim3(256), 0, stream,
                           part, Csum);
        hipLaunchKernelGGL(compose_kernel,    dim3(B_ * MT_),  dim3(320), 0, stream,
                           Csum, cc, lab_ps, cost);
    } else {
        hipLaunchKernelGGL(lab_prep_kernel,   dim3(B_, T_, 8), dim3(256), 0, stream,
                           ml, (unsigned short*)ws, lab_ps, 0);
        hipLaunchKernelGGL(class_cost_kernel, dim3(B_ * Q_),   dim3(64),  0, stream, cl, labels, cc);
        hipLaunchKernelGGL(mask_cost_mono_kernel, dim3(B_ * Q_), dim3(1024), 0, stream,
                           mq, ml, cc, lab_ps, cost);
    }
    hipLaunchKernelGGL(hungarian_kernel, dim3(B_), dim3(64), 0, stream, cost, out);
}

// Round 8
// 77.015 us; speedup vs baseline: 2.3160x; 1.0266x over previous
//
#include <hip/hip_runtime.h>
#include <hip/hip_bf16.h>
#include <math.h>

#define HW_   65536
#define B_    2
#define Q_    100
#define C_    134
#define T_    20
#define NHUN  100
#define MT_   7            // M-tiles of 16 queries (112 >= 100)
#define KSB   128          // K-split blocks per (b,mt)
#define BKCH  512          // k per block
#define WKCH  128          // k per wave (4 MFMA k-steps)
#define PREC  1088         // part record stride (1024 frag + 16 F + 16 P + pad)

typedef __attribute__((ext_vector_type(8))) short bf16x8;
typedef __attribute__((ext_vector_type(4))) float f32x4;

// ws layout (float units)
#define LABPS_OFF  0                    // [2][20][8]
#define CC_OFF     512                  // [200][20] (fallback path only)
#define COST_OFF   4608                 // [200][20]
#define BASE_END   8704
#define LABT_HI_F  BASE_END                         // 2*20*65536 ushort = 1,310,720 floats
#define PART_OFF   (LABT_HI_F + 1310720)            // 1792 records * 1088 floats
#define CSUM_OFF   (PART_OFF + B_ * KSB * MT_ * PREC)   // 14*1056
#define WS_END_F   (CSUM_OFF + B_ * MT_ * 1056)

__device__ inline unsigned short f2bf(float f) {
    unsigned int u = __builtin_bit_cast(unsigned int, f);
    u += 0x7FFFu + ((u >> 16) & 1u);               // RNE
    return (unsigned short)(u >> 16);
}
__device__ inline float softplusf(float x) {
    float ax = fabsf(x);
    return fmaxf(x, 0.0f) + log1pf(expf(-ax));
}

// ---------------- K1: decimate labels -> bf16 rows [b][t][65536] + row-sum partials ----------------
__global__ void lab_prep_kernel(const float* __restrict__ ml, unsigned short* __restrict__ labT,
                                float* __restrict__ lab_ps, int writeT) {
    int b = blockIdx.x, t = blockIdx.y, ksl = blockIdx.z;
    int tid = threadIdx.x;
    const float* src = ml + (size_t)(b * T_ + t) * 262144;
    size_t dst = ((size_t)(b * T_ + t)) << 16;
    float acc = 0.f;
    for (int it = 0; it < 8; ++it) {
        int k = ksl * 8192 + it * 1024 + tid * 4;
        int r = k >> 8, c = k & 255;
        const float* s = src + r * 1024 + 2 * c;
        float4 u = *(const float4*)s;
        float4 w = *(const float4*)(s + 4);
        float v[4] = {u.x, u.z, w.x, w.z};
        unsigned short h[4];
#pragma unroll
        for (int e = 0; e < 4; ++e) { h[e] = f2bf(v[e]); acc += v[e]; }
        if (writeT) *(ushort4*)(labT + dst + k) = make_ushort4(h[0], h[1], h[2], h[3]);
    }
    for (int off = 32; off > 0; off >>= 1) acc += __shfl_down(acc, off);
    __shared__ float sb[4];
    int wid = tid >> 6, lane = tid & 63;
    if (lane == 0) sb[wid] = acc;
    __syncthreads();
    if (tid == 0) lab_ps[(b * T_ + t) * 8 + ksl] = sb[0] + sb[1] + sb[2] + sb[3];
}

// ---------------- class cost (fallback path only) ----------------
__global__ void class_cost_kernel(const float* __restrict__ cl, const int* __restrict__ labels,
                                  float* __restrict__ cc) {
    int bq  = blockIdx.x;
    int b   = bq / Q_;
    int tid = threadIdx.x;         // 64
    __shared__ float sl[C_];
    const float* src = cl + (size_t)bq * C_;
    for (int c = tid; c < C_; c += 64) sl[c] = src[c];
    __syncthreads();
    float mx = -INFINITY;
    for (int c = tid; c < C_; c += 64) mx = fmaxf(mx, sl[c]);
    for (int off = 32; off > 0; off >>= 1) mx = fmaxf(mx, __shfl_xor(mx, off));
    float se = 0.f;
    for (int c = tid; c < C_; c += 64) se += expf(sl[c] - mx);
    for (int off = 32; off > 0; off >>= 1) se += __shfl_xor(se, off);
    float inv = 1.0f / se;
    if (tid < T_) {
        int lbl = labels[b * T_ + tid];
        cc[bq * T_ + tid] = -expf(sl[lbl] - mx) * inv;
    }
}

// ---------------- K3: fused pointwise + single-pass bf16 MFMA partials ----------------
__global__ __launch_bounds__(256) void focal_mfma_kernel(
        const float* __restrict__ mq, const unsigned short* __restrict__ labT,
        float* __restrict__ part) {
    int idx = blockIdx.x;
    int mt  = idx % MT_;
    int rem = idx / MT_;
    int ks  = rem % KSB;
    int b   = rem / KSB;
    int tid  = threadIdx.x;
    int wave = tid >> 6, lane = tid & 63;
    int lg = lane >> 4, lr = lane & 15;

    int q = mt * 16 + lr;
    bool qok = (q < Q_);
    const float* xrow = mq + ((size_t)(b * Q_ + (qok ? q : 0)) << 16);
    int koff = ks * BKCH + wave * WKCH + lg * 8;

    const unsigned short* b1 = labT + (((size_t)(b * T_ + lr)) << 16);
    const unsigned short* b2 = labT + (((size_t)(b * T_ + 16 + (lr & 3))) << 16);
    bool n2row = (lr < 4);

    f32x4 accD0 = {0,0,0,0}, accD1 = {0,0,0,0};
    f32x4 accP0 = {0,0,0,0}, accP1 = {0,0,0,0};
    float F = 0.f, P = 0.f;

    bf16x8 zer;
#pragma unroll
    for (int e = 0; e < 8; ++e) zer[e] = 0;

    for (int kk = 0; kk < 4; ++kk) {
        int kb = koff + kk * 32;
        float4 u0 = *(const float4*)(xrow + kb);
        float4 u1 = *(const float4*)(xrow + kb + 4);
        float xv[8] = {u0.x, u0.y, u0.z, u0.w, u1.x, u1.y, u1.z, u1.w};

        bf16x8 f1 = *(const bf16x8*)(b1 + kb);
        bf16x8 f2 = n2row ? *(const bf16x8*)(b2 + kb) : zer;

        bf16x8 dh, ph;
#pragma unroll
        for (int e = 0; e < 8; ++e) {
            float x  = xv[e];
            float ax = fabsf(x);
            float a  = __expf(-ax);
            float rr = 1.0f / (1.0f + a);
            float p  = (x >= 0.f) ? rr : a * rr;
            float om = (x >= 0.f) ? a * rr : rr;
            float l1 = __logf(1.0f + a);
            float spn = fmaxf(-x, 0.f) + l1;
            float spp = spn + x;
            float fp = 0.25f * om * om * spn;
            float fn = 0.75f * p * p * spp;
            F += fn; P += p;
            dh[e] = (short)f2bf(fp - fn);
            ph[e] = (short)f2bf(p);
        }
        accD0 = __builtin_amdgcn_mfma_f32_16x16x32_bf16(dh, f1, accD0, 0, 0, 0);
        accD1 = __builtin_amdgcn_mfma_f32_16x16x32_bf16(dh, f2, accD1, 0, 0, 0);
        accP0 = __builtin_amdgcn_mfma_f32_16x16x32_bf16(ph, f1, accP0, 0, 0, 0);
        accP1 = __builtin_amdgcn_mfma_f32_16x16x32_bf16(ph, f2, accP1, 0, 0, 0);
    }

    F += __shfl_down(F, 32); F += __shfl_down(F, 16);
    P += __shfl_down(P, 32); P += __shfl_down(P, 16);

    __shared__ float red[4][4][64][4];
    __shared__ float fpb[4][2][16];
#pragma unroll
    for (int r = 0; r < 4; ++r) {
        red[wave][0][lane][r] = accD0[r];
        red[wave][1][lane][r] = accD1[r];
        red[wave][2][lane][r] = accP0[r];
        red[wave][3][lane][r] = accP1[r];
    }
    if (lane < 16) { fpb[wave][0][lane] = F; fpb[wave][1][lane] = P; }
    __syncthreads();
    for (int e = tid; e < 1024; e += 256) {
        int f  = e >> 8;
        int l2 = (e & 255) >> 2;
        int r  = e & 3;
        part[(size_t)idx * PREC + e] =
            red[0][f][l2][r] + red[1][f][l2][r] + red[2][f][l2][r] + red[3][f][l2][r];
    }
    if (tid < 16)
        part[(size_t)idx * PREC + 1024 + tid] =
            fpb[0][0][tid] + fpb[1][0][tid] + fpb[2][0][tid] + fpb[3][0][tid];
    else if (tid < 32) {
        int l = tid - 16;
        part[(size_t)idx * PREC + 1040 + l] =
            fpb[0][1][l] + fpb[1][1][l] + fpb[2][1][l] + fpb[3][1][l];
    }
}

// ---------------- K4a: parallel K-split reduction: part -> Csum[14][1056] ----------------
__global__ __launch_bounds__(256) void reduce_part_kernel(const float* __restrict__ part,
                                                          float* __restrict__ Csum) {
    int bm   = blockIdx.x;          // 0..13
    int mt   = bm % MT_;
    int b    = bm / MT_;
    int tid  = threadIdx.x;
    int epos = tid & 31;
    int grp  = tid >> 5;            // 0..7
    int e    = blockIdx.y * 32 + epos;   // 0..1055

    const float* base = part + (size_t)((b * KSB) * MT_ + mt) * PREC + e;
    float s = 0.f;
    for (int k = 0; k < 16; ++k) {
        s += base[(size_t)(grp * 16 + k) * MT_ * PREC];
    }
    __shared__ float red[8][33];
    red[grp][epos] = s;
    __syncthreads();
    if (tid < 32) {
        float tot = 0.f;
        for (int g = 0; g < 8; ++g) tot += red[g][tid];
        Csum[(size_t)bm * 1056 + e] = tot;
    }
}

// ---------------- K4b: finalize cost from Csum + fused class-softmax ----------------
// grid 14, 320 thr; C/D map: col n = lane&15, row m = (lane>>4)*4 + reg
__global__ __launch_bounds__(320) void compose_kernel(
        const float* __restrict__ Csum, const float* __restrict__ cl,
        const int* __restrict__ labels, const float* __restrict__ lab_ps,
        float* __restrict__ cost) {
    int bm = blockIdx.x;
    int mt = bm % MT_;
    int b  = bm / MT_;
    int tid = threadIdx.x;     // 320
    int q0 = mt * 16;

    __shared__ float sl[16][136];
    __shared__ float mx[16], se[16];
    __shared__ int   lbl[T_];
    for (int e = tid; e < 16 * C_; e += 320) {
        int qm = e / C_, c = e % C_;
        int q = q0 + qm;
        sl[qm][c] = (q < Q_) ? cl[(size_t)(b * Q_ + q) * C_ + c] : 0.f;
    }
    if (tid < T_) lbl[tid] = labels[b * T_ + tid];
    __syncthreads();
    if (tid < 16) {
        float m = -INFINITY;
        for (int c = 0; c < C_; ++c) m = fmaxf(m, sl[tid][c]);
        float s = 0.f;
        for (int c = 0; c < C_; ++c) s += expf(sl[tid][c] - m);
        mx[tid] = m; se[tid] = s;
    }
    __syncthreads();

    int qm = tid / T_, t = tid % T_;
    int q = q0 + qm;
    if (qm < 16 && q < Q_) {
        const float* C = Csum + (size_t)bm * 1056;
        int nt   = t >> 4;
        int lane = ((qm >> 2) << 4) | (t & 15);
        int reg  = qm & 3;
        float Sd = C[(0 + nt) * 256 + lane * 4 + reg];
        float Sp = C[(2 + nt) * 256 + lane * 4 + reg];
        float F  = C[1024 + qm];
        float P  = C[1040 + qm];
        float L = 0.f;
        for (int s8 = 0; s8 < 8; ++s8) L += lab_ps[(b * T_ + t) * 8 + s8];
        float ccv = -expf(sl[qm][lbl[t]] - mx[qm]) / se[qm];
        float cm = (Sd + F) * (1.0f / (float)HW_);
        float cd = 1.0f - (2.0f * Sp + 1.0f) / (P + L + 1.0f);
        cost[(size_t)(b * Q_ + q) * T_ + t] = cm + cd + ccv;
    }
}

// ---------------- fallback: monolithic (round-2 proven) ----------------
__global__ __launch_bounds__(1024) void mask_cost_mono_kernel(
        const float* __restrict__ mq, const float* __restrict__ ml,
        const float* __restrict__ cc, const float* __restrict__ lab_ps,
        float* __restrict__ cost) {
    int bq  = blockIdx.x;
    int b   = bq / Q_;
    int tid = threadIdx.x;
    const float* xb  = mq + (size_t)bq * HW_;
    const float* mlb = ml + (size_t)b * T_ * 262144;
    float s1[T_], s2[T_];
#pragma unroll
    for (int t = 0; t < T_; ++t) { s1[t] = 0.f; s2[t] = 0.f; }
    float F = 0.f, P = 0.f;
    for (int k = tid; k < HW_; k += 1024) {
        int i = k >> 8, j = k & 255;
        float x = xb[k];
        float p = 1.0f / (1.0f + expf(-x));
        float spn = softplusf(-x);
        float spp = softplusf(x);
        float om = 1.0f - p;
        float fp = 0.25f * om * om * spn;
        float fn = 0.75f * p * p * spp;
        F += fn; P += p;
        float diff = fp - fn;
        int off0 = i * 1024 + 2 * j;
#pragma unroll
        for (int t = 0; t < T_; ++t) {
            float lab = mlb[t * 262144 + off0];
            s1[t] = fmaf(diff, lab, s1[t]);
            s2[t] = fmaf(p,    lab, s2[t]);
        }
    }
    __shared__ float sbuf[16][42];
    int wid = tid >> 6, lane = tid & 63;
#pragma unroll
    for (int t = 0; t < T_; ++t) {
        for (int off = 32; off > 0; off >>= 1) {
            s1[t] += __shfl_down(s1[t], off);
            s2[t] += __shfl_down(s2[t], off);
        }
    }
    for (int off = 32; off > 0; off >>= 1) { F += __shfl_down(F, off); P += __shfl_down(P, off); }
    if (lane == 0) {
#pragma unroll
        for (int t = 0; t < T_; ++t) { sbuf[wid][t] = s1[t]; sbuf[wid][T_ + t] = s2[t]; }
        sbuf[wid][40] = F; sbuf[wid][41] = P;
    }
    __syncthreads();
    if (tid < T_) {
        float S1 = 0.f, S2 = 0.f, Fs = 0.f, Ps = 0.f;
        for (int w = 0; w < 16; ++w) {
            S1 += sbuf[w][tid]; S2 += sbuf[w][T_ + tid];
            Fs += sbuf[w][40];  Ps += sbuf[w][41];
        }
        float L = 0.f;
        for (int sl = 0; sl < 8; ++sl) L += lab_ps[(b * T_ + tid) * 8 + sl];
        float cm = (S1 + Fs) * (1.0f / (float)HW_);
        float cd = 1.0f - (2.0f * S2 + 1.0f) / (Ps + L + 1.0f);
        cost[bq * T_ + tid] = cm + cd + cc[bq * T_ + tid];
    }
}

// ---------------- K5: transposed rectangular JV Hungarian, one wave, float + ballot-argmin ----------------
__global__ __launch_bounds__(64) void hungarian_kernel(const float* __restrict__ cost,
                                                       int* __restrict__ out) {
    int b    = blockIdx.x;
    int lane = threadIdx.x;

    __shared__ float csh[Q_ * T_];
    __shared__ float u[T_ + 1];
    __shared__ int   p[NHUN + 1];
    __shared__ int   way[NHUN + 1];

    for (int idx = lane; idx < Q_ * T_; idx += 64) csh[idx] = cost[b * Q_ * T_ + idx];
    for (int j = lane; j <= NHUN; j += 64) { p[j] = 0; way[j] = 0; }
    if (lane <= T_) u[lane] = 0.f;
    __syncthreads();

    const int ja = lane;            // column A (0 = virtual root on lane 0)
    const int jb = lane + 64;       // column B (valid up to 100)
    const bool jb_ok = (jb <= NHUN);
    float v_a = 0.f, v_b = 0.f;

    for (int i = 1; i <= T_; ++i) {
        if (lane == 0) p[0] = i;
        float m_a = INFINITY, m_b = INFINITY;
        bool us_a = false, us_b = false;
        __syncthreads();
        int j0 = 0;
        while (true) {
            if (ja == j0) us_a = true;
            if (jb == j0) us_b = true;
            int   i0  = p[j0];
            float ui0 = u[i0];
            bool fa = (!us_a && ja >= 1);
            bool fb = (jb_ok && !us_b);
            if (fa) {
                float cur = csh[(ja - 1) * T_ + (i0 - 1)] - ui0 - v_a;
                if (cur < m_a) { m_a = cur; way[ja] = j0; }
            }
            if (fb) {
                float cur = csh[(jb - 1) * T_ + (i0 - 1)] - ui0 - v_b;
                if (cur < m_b) { m_b = cur; way[jb] = j0; }
            }
            float ca = fa ? m_a : INFINITY;
            float cb = fb ? m_b : INFINITY;
            float vmin = fminf(ca, cb);
            for (int off = 32; off > 0; off >>= 1)
                vmin = fminf(vmin, __shfl_xor(vmin, off));
            unsigned long long ba = __ballot(ca == vmin);
            int j1;
            if (ba) j1 = __ffsll(ba) - 1;                       // smallest column 1..63
            else    j1 = __ffsll(__ballot(cb == vmin)) - 1 + 64; // smallest column 64..100
            float delta = vmin;
            if (us_a) { u[p[ja]] += delta; v_a -= delta; } else { m_a -= delta; }
            if (jb_ok) {
                if (us_b) { u[p[jb]] += delta; v_b -= delta; } else { m_b -= delta; }
            }
            __threadfence_block();          // single wave: lgkmcnt ordering for u[]/way[]
            j0 = j1;
            if (p[j0] == 0) break;
        }
        if (lane == 0) {
            int jj = j0;
            while (jj) { int jn = way[jj]; p[jj] = p[jn]; jj = jn; }
        }
        __syncthreads();
    }

    if (lane == 0) {
        int* ob = out + b * 2 * T_;
        int k = 0;
        for (int j = 1; j <= NHUN; ++j) {
            if (p[j] != 0) { ob[k] = j - 1; ob[T_ + k] = p[j] - 1; ++k; }
        }
    }
}

extern "C" void kernel_launch(void* const* d_in, const int* in_sizes, int n_in,
                              void* d_out, int out_size, void* d_ws, size_t ws_size,
                              hipStream_t stream) {
    const float* mq     = (const float*)d_in[0];   // [2,100,256,256]
    const float* cl     = (const float*)d_in[1];   // [2,100,134]
    const float* ml     = (const float*)d_in[2];   // [2,20,512,512]
    const int*   labels = (const int*)d_in[3];     // [2,20]
    int* out = (int*)d_out;                        // [2,2,20] int32
    float* ws = (float*)d_ws;

    float* lab_ps = ws + LABPS_OFF;
    float* cc     = ws + CC_OFF;
    float* cost   = ws + COST_OFF;

    size_t need = (size_t)WS_END_F * 4;

    if (ws_size >= need) {
        unsigned short* labT = (unsigned short*)(ws + LABT_HI_F);
        float* part = ws + PART_OFF;
        float* Csum = ws + CSUM_OFF;
        hipLaunchKernelGGL(lab_prep_kernel,   dim3(B_, T_, 8), dim3(256), 0, stream,
                           ml, labT, lab_ps, 1);
        hipLaunchKernelGGL(focal_mfma_kernel, dim3(B_ * KSB * MT_), dim3(256), 0, stream,
                           mq, labT, part);
        hipLaunchKernelGGL(reduce_part_kernel, dim3(B_ * MT_, 33), dim3(256), 0, stream,
                           part, Csum);
        hipLaunchKernelGGL(compose_kernel,    dim3(B_ * MT_),  dim3(320), 0, stream,
                           Csum, cl, labels, lab_ps, cost);
    } else {
        hipLaunchKernelGGL(lab_prep_kernel,   dim3(B_, T_, 8), dim3(256), 0, stream,
                           ml, (unsigned short*)ws, lab_ps, 0);
        hipLaunchKernelGGL(class_cost_kernel, dim3(B_ * Q_),   dim3(64),  0, stream, cl, labels, cc);
        hipLaunchKernelGGL(mask_cost_mono_kernel, dim3(B_ * Q_), dim3(1024), 0, stream,
                           mq, ml, cc, lab_ps, cost);
    }
    hipLaunchKernelGGL(hungarian_kernel, dim3(B_), dim3(64), 0, stream, cost, out);
}